// Round 1
// baseline (2402.537 us; speedup 1.0000x reference)
//
#include <hip/hip_runtime.h>
#include <hip/hip_bf16.h>
#include <math.h>

#define HW 16384
#define CDIM 96
#define NB 8

// ---------------------------------------------------------------- fc2 transpose
__global__ __launch_bounds__(256) void k_transpose_fc2(const float* __restrict__ w,
                                                       float* __restrict__ wt) {
    int t = blockIdx.x * 256 + threadIdx.x;   // 96*384 = 36864
    if (t < 96 * 384) {
        int o = t / 384, j = t % 384;
        wt[j * 96 + o] = w[t];
    }
}

// ---------------------------------------------------------------- LN1 + QKV
__global__ __launch_bounds__(256) void k_ln1_qkv(const float* __restrict__ x,
                                                 const float* __restrict__ qkv_w,
                                                 const float* __restrict__ ln1w,
                                                 const float* __restrict__ ln1b,
                                                 __hip_bfloat16* __restrict__ qkv) {
    int t = blockIdx.x * 256 + threadIdx.x;   // pixel id
    int b = t >> 14;
    int pix = t & 16383;
    const float* xb = x + (size_t)b * CDIM * HW + pix;

    float y[CDIM];
    float mu = 0.f;
#pragma unroll
    for (int c = 0; c < CDIM; c++) { y[c] = xb[(size_t)c * HW]; mu += y[c]; }
    mu *= (1.f / 96.f);
    float var = 0.f;
#pragma unroll
    for (int c = 0; c < CDIM; c++) { float d = y[c] - mu; var += d * d; }
    float inv = rsqrtf(var * (1.f / 96.f) + 1e-5f);
#pragma unroll
    for (int c = 0; c < CDIM; c++) y[c] = (y[c] - mu) * inv * ln1w[c] + ln1b[c];

    __hip_bfloat16* qb = qkv + (size_t)b * 288 * HW + pix;
#pragma unroll 1
    for (int o0 = 0; o0 < 288; o0 += 8) {
        float acc[8];
#pragma unroll
        for (int i = 0; i < 8; i++) acc[i] = 0.f;
#pragma unroll
        for (int c = 0; c < CDIM; c++) {
            float yc = y[c];
#pragma unroll
            for (int i = 0; i < 8; i++) acc[i] += yc * qkv_w[(o0 + i) * 96 + c];
        }
#pragma unroll
        for (int i = 0; i < 8; i++) qb[(size_t)(o0 + i) * HW] = __float2bfloat16(acc[i]);
    }
}

// ---------------------------------------------------------------- attention + proj + residual
__global__ __launch_bounds__(256) void k_attn_proj(const __hip_bfloat16* __restrict__ qkv,
                                                   const float* __restrict__ x,
                                                   const float* __restrict__ proj_w,
                                                   const float* __restrict__ proj_b,
                                                   float* __restrict__ x1) {
    int t = blockIdx.x * 256 + threadIdx.x;
    int b = t >> 14;
    int pix = t & 16383;
    int hh = pix >> 7, ww = pix & 127;

    const __hip_bfloat16* qkvb = qkv + (size_t)b * 288 * HW;
    float yout[CDIM];

#pragma unroll 1
    for (int di = 0; di < 3; di++) {
        int d = di + 1;
#pragma unroll 1
        for (int hd = 0; hd < 2; hd++) {
            int cb = di * 32 + hd * 16;
            const __hip_bfloat16* qp = qkvb + (size_t)cb * HW;
            const __hip_bfloat16* kp = qkvb + (size_t)(96 + cb) * HW;
            const __hip_bfloat16* vp = qkvb + (size_t)(192 + cb) * HW;

            float q[16];
#pragma unroll
            for (int c = 0; c < 16; c++) q[c] = __bfloat162float(qp[(size_t)c * HW + pix]);

            float sc[9];
            int noff[9];
            bool okk[9];
#pragma unroll
            for (int i = 0; i < 3; i++) {
#pragma unroll
                for (int j = 0; j < 3; j++) {
                    int k9 = i * 3 + j;
                    int yy = hh + (i - 1) * d;
                    int xx = ww + (j - 1) * d;
                    bool ok = ((unsigned)yy < 128u) && ((unsigned)xx < 128u);
                    okk[k9] = ok;
                    noff[k9] = yy * 128 + xx;
                    float s = 0.f;
                    if (ok) {
#pragma unroll
                        for (int c = 0; c < 16; c++)
                            s += q[c] * __bfloat162float(kp[(size_t)c * HW + noff[k9]]);
                    }
                    sc[k9] = s * 0.25f;   // SCALE = 16^-0.5
                }
            }
            // softmax over 9 (zero-padded taps participate with score 0)
            float mx = sc[0];
#pragma unroll
            for (int k9 = 1; k9 < 9; k9++) mx = fmaxf(mx, sc[k9]);
            float sum = 0.f;
#pragma unroll
            for (int k9 = 0; k9 < 9; k9++) { sc[k9] = __expf(sc[k9] - mx); sum += sc[k9]; }
            float rs = 1.f / sum;

            float o[16];
#pragma unroll
            for (int c = 0; c < 16; c++) o[c] = 0.f;
#pragma unroll
            for (int k9 = 0; k9 < 9; k9++) {
                if (okk[k9]) {
                    float w9 = sc[k9];
#pragma unroll
                    for (int c = 0; c < 16; c++)
                        o[c] += w9 * __bfloat162float(vp[(size_t)c * HW + noff[k9]]);
                }
            }
#pragma unroll
            for (int c = 0; c < 16; c++) yout[cb + c] = o[c] * rs;
        }
    }

    // proj + residual
    const float* xb = x + (size_t)b * CDIM * HW + pix;
    float* x1b = x1 + (size_t)b * CDIM * HW + pix;
#pragma unroll 1
    for (int o0 = 0; o0 < 96; o0 += 8) {
        float acc[8];
#pragma unroll
        for (int i = 0; i < 8; i++) acc[i] = proj_b[o0 + i];
#pragma unroll
        for (int c = 0; c < CDIM; c++) {
            float yc = yout[c];
#pragma unroll
            for (int i = 0; i < 8; i++) acc[i] += yc * proj_w[(o0 + i) * 96 + c];
        }
#pragma unroll
        for (int i = 0; i < 8; i++)
            x1b[(size_t)(o0 + i) * HW] = acc[i] + xb[(size_t)(o0 + i) * HW];
    }
}

// ---------------------------------------------------------------- LN2 + MLP + residual
__global__ __launch_bounds__(256) void k_mlp(const float* __restrict__ x1,
                                             const float* __restrict__ ln2w,
                                             const float* __restrict__ ln2b,
                                             const float* __restrict__ fc1w,
                                             const float* __restrict__ fc1b,
                                             const float* __restrict__ fc2t,  // (384,96)
                                             const float* __restrict__ fc2b,
                                             float* __restrict__ out) {
    int t = blockIdx.x * 256 + threadIdx.x;
    int b = t >> 14;
    int pix = t & 16383;
    const float* xb = x1 + (size_t)b * CDIM * HW + pix;

    float y[CDIM];
    float mu = 0.f;
#pragma unroll
    for (int c = 0; c < CDIM; c++) { y[c] = xb[(size_t)c * HW]; mu += y[c]; }
    mu *= (1.f / 96.f);
    float var = 0.f;
#pragma unroll
    for (int c = 0; c < CDIM; c++) { float d = y[c] - mu; var += d * d; }
    float inv = rsqrtf(var * (1.f / 96.f) + 1e-5f);

    float acc[CDIM];
#pragma unroll
    for (int c = 0; c < CDIM; c++) {
        acc[c] = y[c] + fc2b[c];                       // residual + fc2 bias
        y[c] = (y[c] - mu) * inv * ln2w[c] + ln2b[c];  // LN2
    }

#pragma unroll 1
    for (int j0 = 0; j0 < 384; j0 += 4) {
        float h[4];
#pragma unroll
        for (int i = 0; i < 4; i++) h[i] = fc1b[j0 + i];
#pragma unroll
        for (int c = 0; c < CDIM; c++) {
            float yc = y[c];
#pragma unroll
            for (int i = 0; i < 4; i++) h[i] += yc * fc1w[(j0 + i) * 96 + c];
        }
#pragma unroll
        for (int i = 0; i < 4; i++) {
            float v = h[i];
            h[i] = 0.5f * v * (1.f + erff(v * 0.70710678118654752f));  // exact GeLU
        }
#pragma unroll
        for (int i = 0; i < 4; i++) {
            float g = h[i];
#pragma unroll
            for (int c = 0; c < CDIM; c++) acc[c] += g * fc2t[(j0 + i) * 96 + c];
        }
    }

    float* ob = out + (size_t)b * CDIM * HW + pix;
#pragma unroll
    for (int c = 0; c < CDIM; c++) ob[(size_t)c * HW] = acc[c];
}

// ---------------------------------------------------------------- launch
extern "C" void kernel_launch(void* const* d_in, const int* in_sizes, int n_in,
                              void* d_out, int out_size, void* d_ws, size_t ws_size,
                              hipStream_t stream) {
    const float* x      = (const float*)d_in[0];
    const float* qkv_w  = (const float*)d_in[1];
    const float* proj_w = (const float*)d_in[2];
    const float* proj_b = (const float*)d_in[3];
    const float* ln1w   = (const float*)d_in[4];
    const float* ln1b   = (const float*)d_in[5];
    const float* ln2w   = (const float*)d_in[6];
    const float* ln2b   = (const float*)d_in[7];
    const float* fc1w   = (const float*)d_in[8];
    const float* fc1b   = (const float*)d_in[9];
    const float* fc2w   = (const float*)d_in[10];
    const float* fc2b   = (const float*)d_in[11];
    float* out = (float*)d_out;

    char* ws = (char*)d_ws;
    __hip_bfloat16* qkv = (__hip_bfloat16*)ws;                     // 8*288*16384*2 = 75.5 MB
    size_t off = (size_t)NB * 288 * HW * sizeof(__hip_bfloat16);
    float* x1 = (float*)(ws + off);                                // 8*96*16384*4 = 50.3 MB
    off += (size_t)NB * CDIM * HW * sizeof(float);
    float* fc2t = (float*)(ws + off);                              // 147 KB

    k_transpose_fc2<<<144, 256, 0, stream>>>(fc2w, fc2t);
    k_ln1_qkv<<<512, 256, 0, stream>>>(x, qkv_w, ln1w, ln1b, qkv);
    k_attn_proj<<<512, 256, 0, stream>>>(qkv, x, proj_w, proj_b, x1);
    k_mlp<<<512, 256, 0, stream>>>(x1, ln2w, ln2b, fc1w, fc1b, fc2t, fc2b, out);
}

// Round 2
// 642.824 us; speedup vs baseline: 3.7375x; 3.7375x over previous
//
#include <hip/hip_runtime.h>
#include <hip/hip_bf16.h>
#include <math.h>

typedef __attribute__((ext_vector_type(8))) short bf16x8;
typedef __attribute__((ext_vector_type(4))) float f32x4;

#define MTOT  131072
#define HW16K 16384

__device__ inline float bf2f(unsigned short u) {
    union { unsigned u; float f; } x; x.u = ((unsigned)u) << 16; return x.f;
}
__device__ inline unsigned short f2bf(float a) {
    __hip_bfloat16 h = __float2bfloat16(a);
    union { __hip_bfloat16 h; unsigned short u; } c; c.h = h; return c.u;
}
__device__ inline unsigned pack2bf(float a, float b) {
    __hip_bfloat162 h = __float22bfloat162_rn(make_float2(a, b));
    union { __hip_bfloat162 h; unsigned u; } c; c.h = h; return c.u;
}
__device__ inline void load16(const unsigned short* p, float* f) {
    uint4 u0 = *(const uint4*)p;
    uint4 u1 = *(const uint4*)(p + 8);
    unsigned w[8] = {u0.x, u0.y, u0.z, u0.w, u1.x, u1.y, u1.z, u1.w};
#pragma unroll
    for (int i = 0; i < 8; i++) {
        union { unsigned u; float f; } lo, hi;
        lo.u = w[i] << 16; hi.u = w[i] & 0xffff0000u;
        f[2 * i] = lo.f; f[2 * i + 1] = hi.f;
    }
}

// ------------------------------------------------ weights fp32 -> bf16
__global__ __launch_bounds__(256) void k_prep(const float* __restrict__ qw,
                                              const float* __restrict__ pw,
                                              const float* __restrict__ f1,
                                              const float* __restrict__ f2,
                                              unsigned short* __restrict__ wq,
                                              unsigned short* __restrict__ wp,
                                              unsigned short* __restrict__ w1,
                                              unsigned short* __restrict__ w2) {
    int t = blockIdx.x * 256 + threadIdx.x;
    if (t < 27648) wq[t] = f2bf(qw[t]);
    else if (t < 36864) wp[t - 27648] = f2bf(pw[t - 27648]);
    else if (t < 73728) w1[t - 36864] = f2bf(f1[t - 36864]);
    else if (t < 110592) w2[t - 73728] = f2bf(f2[t - 73728]);
}

// ------------------------------------------------ LN1: planar x -> pixel-major y bf16
// 128 pixels/block, 256 threads: thread (p = tid&127, half = tid>>7) loads 48 channels.
__global__ __launch_bounds__(256) void k_ln1(const float* __restrict__ x,
                                             const float* __restrict__ w,
                                             const float* __restrict__ bln,
                                             unsigned* __restrict__ y) {
    __shared__ float buf[128 * 97];
    __shared__ float ps[256], ps2[256];
    int tid = threadIdx.x;
    int p = tid & 127, half = tid >> 7;
    int gp0 = blockIdx.x * 128;
    int b = gp0 >> 14, pix0 = gp0 & 16383;

    float val[48];
    float s = 0.f, s2 = 0.f;
#pragma unroll
    for (int i = 0; i < 48; i++) {
        int c = half * 48 + i;
        float v = x[((size_t)b * 96 + c) * HW16K + pix0 + p];
        val[i] = v; s += v; s2 += v * v;
    }
    ps[tid] = s; ps2[tid] = s2;
    __syncthreads();
    float st = ps[p] + ps[p + 128];
    float st2 = ps2[p] + ps2[p + 128];
    float mu = st * (1.f / 96.f);
    float inv = rsqrtf(st2 * (1.f / 96.f) - mu * mu + 1e-5f);
#pragma unroll
    for (int i = 0; i < 48; i++) {
        int c = half * 48 + i;
        buf[p * 97 + c] = (val[i] - mu) * inv * w[c] + bln[c];
    }
    __syncthreads();
    // cooperative coalesced store: 128*48 = 6144 uints
#pragma unroll 1
    for (int it = 0; it < 24; it++) {
        int w2 = it * 256 + tid;
        int pp = w2 / 48, cp = w2 % 48;
        float f0 = buf[pp * 97 + cp * 2];
        float f1 = buf[pp * 97 + cp * 2 + 1];
        y[(size_t)gp0 * 48 + w2] = pack2bf(f0, f1);
    }
}

// ------------------------------------------------ generic MFMA GEMM, B resident in LDS
// A: [m][K] bf16 pixel-major, Bw: [N][K] bf16 row-major.
// EPI: 0 = store bf16 [m][N]; 1 = +bias +planar-x residual -> fp32 [m][96];
//      2 = +bias, GeLU -> bf16 [m][N]; 3 = +bias + x1 residual -> planar fp32 out.
template<int N, int K, int TPB, int EPI>
__global__ __launch_bounds__(256) void k_gemm(const unsigned short* __restrict__ A,
                                              const unsigned short* __restrict__ Bw,
                                              const float* __restrict__ bias,
                                              const float* __restrict__ extra,
                                              void* __restrict__ out, int m0) {
    constexpr int KF = K / 32, NT = N / 16;
    __shared__ unsigned short Bs[N * K];
    int tid = threadIdx.x;
    for (int i = tid; i < N * K / 8; i += 256)
        ((uint4*)Bs)[i] = ((const uint4*)Bw)[i];
    __syncthreads();

    int lane = tid & 63, wv = tid >> 6;
    int kq = (lane >> 4) * 8;

#pragma unroll 1
    for (int it = 0; it < TPB / 4; it++) {
        int lt = blockIdx.x * TPB + wv * (TPB / 4) + it;
        f32x4 acc[NT];
#pragma unroll
        for (int nt = 0; nt < NT; nt++) acc[nt] = (f32x4){0.f, 0.f, 0.f, 0.f};

        bf16x8 a[KF];
        const unsigned short* ar = A + (size_t)(lt * 16 + (lane & 15)) * K + kq;
#pragma unroll
        for (int f = 0; f < KF; f++) a[f] = *(const bf16x8*)(ar + f * 32);

#pragma unroll
        for (int nt = 0; nt < NT; nt++) {
            const unsigned short* br = Bs + (size_t)(nt * 16 + (lane & 15)) * K + kq;
#pragma unroll
            for (int f = 0; f < KF; f++) {
                bf16x8 bfr = *(const bf16x8*)(br + f * 32);
                acc[nt] = __builtin_amdgcn_mfma_f32_16x16x32_bf16(a[f], bfr, acc[nt], 0, 0, 0);
            }
        }

        if constexpr (EPI == 0) {
            unsigned short* o = (unsigned short*)out;
#pragma unroll
            for (int nt = 0; nt < NT; nt++) {
                int col = nt * 16 + (lane & 15);
#pragma unroll
                for (int r = 0; r < 4; r++) {
                    int lm = lt * 16 + (lane >> 4) * 4 + r;
                    o[(size_t)lm * N + col] = f2bf(acc[nt][r]);
                }
            }
        } else if constexpr (EPI == 1) {
            float* o = (float*)out;
#pragma unroll
            for (int nt = 0; nt < NT; nt++) {
                int col = nt * 16 + (lane & 15);
                float bs = bias[col];
#pragma unroll
                for (int r = 0; r < 4; r++) {
                    int lm = lt * 16 + (lane >> 4) * 4 + r;
                    int gm = m0 + lm;
                    int b = gm >> 14, pix = gm & 16383;
                    o[(size_t)gm * 96 + col] =
                        acc[nt][r] + bs + extra[((size_t)b * 96 + col) * HW16K + pix];
                }
            }
        } else if constexpr (EPI == 2) {
            unsigned short* o = (unsigned short*)out;
#pragma unroll
            for (int nt = 0; nt < NT; nt++) {
                int col = nt * 16 + (lane & 15);
                float bs = bias[col];
#pragma unroll
                for (int r = 0; r < 4; r++) {
                    int lm = lt * 16 + (lane >> 4) * 4 + r;
                    float v = acc[nt][r] + bs;
                    float g = 0.5f * v * (1.f + erff(v * 0.70710678118654752f));
                    o[(size_t)lm * N + col] = f2bf(g);
                }
            }
        } else {
            float* o = (float*)out;
#pragma unroll
            for (int nt = 0; nt < NT; nt++) {
                int col = nt * 16 + (lane & 15);
                float bs = bias[col];
#pragma unroll
                for (int r = 0; r < 4; r++) {
                    int lm = lt * 16 + (lane >> 4) * 4 + r;
                    int gm = m0 + lm;
                    int b = gm >> 14, pix = gm & 16383;
                    o[((size_t)b * 96 + col) * HW16K + pix] =
                        acc[nt][r] + bs + extra[(size_t)gm * 96 + col];
                }
            }
        }
    }
}

// ------------------------------------------------ dilated attention, pixel-major qkv
__global__ __launch_bounds__(256) void k_attn(const unsigned short* __restrict__ qkvb,
                                              unsigned short* __restrict__ attn, int m0) {
    int t = blockIdx.x * 256 + threadIdx.x;   // chunk-local pixel
    int gm = m0 + t;
    int pix = gm & 16383;
    int hh = pix >> 7, ww = pix & 127;
    int ibase = t & ~16383;
    const unsigned short* qrow = qkvb + (size_t)t * 288;
    unsigned* orow = (unsigned*)attn + (size_t)gm * 48;

#pragma unroll 1
    for (int di = 0; di < 3; di++) {
        int d = di + 1;
#pragma unroll 1
        for (int hd = 0; hd < 2; hd++) {
            int cb = di * 32 + hd * 16;
            float q[16];
            load16(qrow + cb, q);

            float sc[9]; int nloc[9]; bool ok[9];
#pragma unroll
            for (int i = 0; i < 3; i++) {
#pragma unroll
                for (int j = 0; j < 3; j++) {
                    int k9 = i * 3 + j;
                    int yy = hh + (i - 1) * d;
                    int xx = ww + (j - 1) * d;
                    bool o_ = ((unsigned)yy < 128u) && ((unsigned)xx < 128u);
                    ok[k9] = o_;
                    nloc[k9] = ibase + yy * 128 + xx;
                    float s = 0.f;
                    if (o_) {
                        float kf[16];
                        load16(qkvb + (size_t)nloc[k9] * 288 + 96 + cb, kf);
#pragma unroll
                        for (int c = 0; c < 16; c++) s += q[c] * kf[c];
                    }
                    sc[k9] = s * 0.25f;
                }
            }
            float mx = sc[0];
#pragma unroll
            for (int k9 = 1; k9 < 9; k9++) mx = fmaxf(mx, sc[k9]);
            float sum = 0.f;
#pragma unroll
            for (int k9 = 0; k9 < 9; k9++) { sc[k9] = __expf(sc[k9] - mx); sum += sc[k9]; }
            float rs = 1.f / sum;

            float o[16];
#pragma unroll
            for (int c = 0; c < 16; c++) o[c] = 0.f;
#pragma unroll
            for (int k9 = 0; k9 < 9; k9++) {
                if (ok[k9]) {
                    float vf[16];
                    load16(qkvb + (size_t)nloc[k9] * 288 + 192 + cb, vf);
                    float w9 = sc[k9];
#pragma unroll
                    for (int c = 0; c < 16; c++) o[c] += w9 * vf[c];
                }
            }
#pragma unroll
            for (int c2 = 0; c2 < 8; c2++)
                orow[cb / 2 + c2] = pack2bf(o[2 * c2] * rs, o[2 * c2 + 1] * rs);
        }
    }
}

// ------------------------------------------------ LN2: pixel-major fp32 -> bf16
__global__ __launch_bounds__(256) void k_ln2(const float* __restrict__ x1,
                                             const float* __restrict__ w,
                                             const float* __restrict__ bln,
                                             unsigned* __restrict__ y2) {
    int m = blockIdx.x * 256 + threadIdx.x;
    const float4* r = (const float4*)(x1 + (size_t)m * 96);
    float v[96];
    float s = 0.f, s2 = 0.f;
#pragma unroll
    for (int i = 0; i < 24; i++) {
        float4 t = r[i];
        v[4 * i] = t.x; v[4 * i + 1] = t.y; v[4 * i + 2] = t.z; v[4 * i + 3] = t.w;
        s += t.x + t.y + t.z + t.w;
        s2 += t.x * t.x + t.y * t.y + t.z * t.z + t.w * t.w;
    }
    float mu = s * (1.f / 96.f);
    float inv = rsqrtf(s2 * (1.f / 96.f) - mu * mu + 1e-5f);
    unsigned* yr = y2 + (size_t)m * 48;
#pragma unroll
    for (int j = 0; j < 12; j++) {
        uint4 pk;
        float n0, n1;
        int c = j * 8;
        n0 = (v[c + 0] - mu) * inv * w[c + 0] + bln[c + 0];
        n1 = (v[c + 1] - mu) * inv * w[c + 1] + bln[c + 1];
        pk.x = pack2bf(n0, n1);
        n0 = (v[c + 2] - mu) * inv * w[c + 2] + bln[c + 2];
        n1 = (v[c + 3] - mu) * inv * w[c + 3] + bln[c + 3];
        pk.y = pack2bf(n0, n1);
        n0 = (v[c + 4] - mu) * inv * w[c + 4] + bln[c + 4];
        n1 = (v[c + 5] - mu) * inv * w[c + 5] + bln[c + 5];
        pk.z = pack2bf(n0, n1);
        n0 = (v[c + 6] - mu) * inv * w[c + 6] + bln[c + 6];
        n1 = (v[c + 7] - mu) * inv * w[c + 7] + bln[c + 7];
        pk.w = pack2bf(n0, n1);
        ((uint4*)yr)[j] = pk;
    }
}

// ------------------------------------------------ launch
extern "C" void kernel_launch(void* const* d_in, const int* in_sizes, int n_in,
                              void* d_out, int out_size, void* d_ws, size_t ws_size,
                              hipStream_t stream) {
    const float* x      = (const float*)d_in[0];
    const float* qkv_w  = (const float*)d_in[1];
    const float* proj_w = (const float*)d_in[2];
    const float* proj_b = (const float*)d_in[3];
    const float* ln1w   = (const float*)d_in[4];
    const float* ln1b   = (const float*)d_in[5];
    const float* ln2w   = (const float*)d_in[6];
    const float* ln2b   = (const float*)d_in[7];
    const float* fc1w   = (const float*)d_in[8];
    const float* fc1b   = (const float*)d_in[9];
    const float* fc2w   = (const float*)d_in[10];
    const float* fc2b   = (const float*)d_in[11];
    float* out = (float*)d_out;

    char* ws = (char*)d_ws;
    unsigned short* wq = (unsigned short*)(ws);                 // 55296 B
    unsigned short* wp = (unsigned short*)(ws + 55296);         // 18432 B
    unsigned short* w1 = (unsigned short*)(ws + 73728);         // 73728 B
    unsigned short* w2 = (unsigned short*)(ws + 147456);        // 73728 B
    unsigned short* y    = (unsigned short*)(ws + 221184);      // 25.17 MB  (later: y2)
    unsigned short* qkvb = (unsigned short*)(ws + 25387008);    // 18.87 MB  (2-image chunk)
    unsigned short* attn = (unsigned short*)(ws + 44261376);    // 25.17 MB  (later: h)
    float*          x1   = (float*)(ws + 69427200);             // 50.33 MB  -> total 119.8 MB

    k_prep<<<432, 256, 0, stream>>>(qkv_w, proj_w, fc1w, fc2w, wq, wp, w1, w2);
    k_ln1<<<1024, 256, 0, stream>>>(x, ln1w, ln1b, (unsigned*)y);

    // attention side: 4 chunks of 2 images (32768 pixels)
    for (int c = 0; c < 4; c++) {
        int m0 = c * 32768;
        k_gemm<288, 96, 8, 0><<<256, 256, 0, stream>>>(
            y + (size_t)m0 * 96, wq, nullptr, nullptr, qkvb, m0);
        k_attn<<<128, 256, 0, stream>>>(qkvb, attn, m0);
    }
    // proj + residual -> x1 (full M)
    k_gemm<96, 96, 8, 1><<<1024, 256, 0, stream>>>(
        attn, wp, proj_b, x, x1, 0);
    // LN2 -> y2 (reuses y region)
    unsigned short* y2 = y;
    k_ln2<<<512, 256, 0, stream>>>(x1, ln2w, ln2b, (unsigned*)y2);
    // MLP: 4 chunks of 32768 pixels; h reuses attn region
    unsigned short* h = attn;
    for (int c = 0; c < 4; c++) {
        int m0 = c * 32768;
        k_gemm<384, 96, 8, 2><<<256, 256, 0, stream>>>(
            y2 + (size_t)m0 * 96, w1, fc1b, nullptr, h, m0);
        k_gemm<96, 384, 8, 3><<<256, 256, 0, stream>>>(
            h, w2, fc2b, x1, out, m0);
    }
}